// Round 5
// baseline (260.550 us; speedup 1.0000x reference)
//
#include <hip/hip_runtime.h>
#include <math.h>

// Problem constants
#define NB 32
#define NC 64          // CODE_DIM
#define NK 2048
#define NCODES 1024
#define NVEC (NB*NK)          // 65536 vectors
#define NELEM (NB*NC*NK)      // 4194304 elements
#define NBLK (NVEC/64)        // 1024 blocks

#define MARGIN 1.5e-3f        // rigorous bound 8.7e-4 (see header comment)
#define CAP 16

// ws layout (bytes)
#define WS_HIST  0            // int[1024]      = 4096
#define WS_CBN32 4096         // float[1024]    = 4096
#define WS_PART  8192         // double[1024]   = 8192
#define WS_CBBF  32768        // __bf16[65536]  = 131072  (ends 163840)

typedef __bf16 bf16x8 __attribute__((ext_vector_type(8)));
typedef float  f32x4  __attribute__((ext_vector_type(4)));
#define MFMA16(A, B, ACC) __builtin_amdgcn_mfma_f32_16x16x32_bf16(A, B, ACC, 0, 0, 0)

// --- codebook prep: numpy-exact fp32 norms (validated R2-R4) + bf16 copy ----
__global__ void k_cbprep(const float* __restrict__ cb, float* __restrict__ n32,
                         __bf16* __restrict__ cbbf) {
    int j = blockIdx.x * 64 + threadIdx.x;   // 16 x 64 = 1024
    const float* cr = cb + (size_t)j * NC;
    float r[8];
#pragma unroll
    for (int q = 0; q < 8; q++) r[q] = __fmul_rn(cr[q], cr[q]);
#pragma unroll
    for (int i = 8; i < 64; i += 8)
#pragma unroll
        for (int q = 0; q < 8; q++)
            r[q] = __fadd_rn(r[q], __fmul_rn(cr[i + q], cr[i + q]));
    float s01 = __fadd_rn(r[0], r[1]), s23 = __fadd_rn(r[2], r[3]);
    float s45 = __fadd_rn(r[4], r[5]), s67 = __fadd_rn(r[6], r[7]);
    n32[j] = __fadd_rn(__fadd_rn(s01, s23), __fadd_rn(s45, s67));
    __bf16* br = cbbf + (size_t)j * NC;
#pragma unroll
    for (int c = 0; c < NC; c++) br[c] = (__bf16)cr[c];
}

// --- fused VQ: MFMA prefilter -> exact-chain rescore -> quant ---------------
// Block: 256 thr = 4 waves; 64 vectors; wave w owns codes [w*256, w*256+256).
// MFMA 16x16x32 bf16 layouts (HW-verified m89/m91/m120):
//   A[m=lane&15][k=quad*8+j], B^T-row style b-frag n=lane&15, k=quad*8+j,
//   D: col(n)=lane&15, row(m)=quad*4+reg.
__launch_bounds__(256, 4)
__global__ void k_vq(const float* __restrict__ ze, const float* __restrict__ cb,
                     const float* __restrict__ n32, const __bf16* __restrict__ cbbf,
                     int* __restrict__ hist, float* __restrict__ codes_f,
                     float* __restrict__ outq, double* __restrict__ part) {
    __shared__ float gpart[4][64];
    __shared__ float gm[64];
    __shared__ int   cnt[64];
    __shared__ int   cand[64][CAP];
    __shared__ int   codearr[64];
    __shared__ double lsd[4];

    const int t = threadIdx.x;
    const int L = t & 63;
    const int w = t >> 6;
    const int quad = L >> 4;
    const int col = L & 15;
    const int vec0 = blockIdx.x * 64;
    const int b = vec0 >> 11;
    const int k0 = vec0 & (NK - 1);
    const float* zbase = ze + (size_t)b * NC * NK + k0;

    if (t < 64) cnt[t] = 0;

    // A-frags: af[mt][kt]; m = mt*16+col, c = kt*32+quad*8+j  (bf16 RNE)
    bf16x8 af[4][2];
#pragma unroll
    for (int mt = 0; mt < 4; mt++)
#pragma unroll
        for (int kt = 0; kt < 2; kt++)
#pragma unroll
            for (int j = 0; j < 8; j++) {
                int c = kt * 32 + quad * 8 + j;
                af[mt][kt][j] = (__bf16)zbase[(size_t)c * NK + mt * 16 + col];
            }

    const int nb = w * 256;
    float nv[16];
#pragma unroll
    for (int nt = 0; nt < 16; nt++) nv[nt] = n32[nb + nt * 16 + col];

    // ---- pass A: per-vector min of pd = n32 - 2*bf16dot --------------------
    float rmin[4][4];
#pragma unroll
    for (int mt = 0; mt < 4; mt++)
#pragma unroll
        for (int r = 0; r < 4; r++) rmin[mt][r] = 3.0e38f;

    for (int nt = 0; nt < 16; nt++) {
        const __bf16* brow = cbbf + (size_t)(nb + nt * 16 + col) * NC + quad * 8;
        bf16x8 b0 = *(const bf16x8*)(brow);
        bf16x8 b1 = *(const bf16x8*)(brow + 32);
#pragma unroll
        for (int mt = 0; mt < 4; mt++) {
            f32x4 acc = {0.f, 0.f, 0.f, 0.f};
            acc = MFMA16(af[mt][0], b0, acc);
            acc = MFMA16(af[mt][1], b1, acc);
#pragma unroll
            for (int r = 0; r < 4; r++) {
                float pd = __fsub_rn(nv[nt], __fmul_rn(2.f, acc[r]));
                rmin[mt][r] = fminf(rmin[mt][r], pd);
            }
        }
    }
#pragma unroll
    for (int mt = 0; mt < 4; mt++)
#pragma unroll
        for (int r = 0; r < 4; r++) {
            float v = rmin[mt][r];
            v = fminf(v, __shfl_xor(v, 1, 16));
            v = fminf(v, __shfl_xor(v, 2, 16));
            v = fminf(v, __shfl_xor(v, 4, 16));
            v = fminf(v, __shfl_xor(v, 8, 16));
            if (col == 0) gpart[w][mt * 16 + quad * 4 + r] = v;
        }
    __syncthreads();
    if (t < 64)
        gm[t] = fminf(fminf(gpart[0][t], gpart[1][t]),
                      fminf(gpart[2][t], gpart[3][t])) + MARGIN;
    __syncthreads();

    float gmr[4][4];
#pragma unroll
    for (int mt = 0; mt < 4; mt++)
#pragma unroll
        for (int r = 0; r < 4; r++) gmr[mt][r] = gm[mt * 16 + quad * 4 + r];

    // ---- pass B: bit-identical recompute, gather candidates ----------------
    for (int nt = 0; nt < 16; nt++) {
        const __bf16* brow = cbbf + (size_t)(nb + nt * 16 + col) * NC + quad * 8;
        bf16x8 b0 = *(const bf16x8*)(brow);
        bf16x8 b1 = *(const bf16x8*)(brow + 32);
#pragma unroll
        for (int mt = 0; mt < 4; mt++) {
            f32x4 acc = {0.f, 0.f, 0.f, 0.f};
            acc = MFMA16(af[mt][0], b0, acc);
            acc = MFMA16(af[mt][1], b1, acc);
#pragma unroll
            for (int r = 0; r < 4; r++) {
                float pd = __fsub_rn(nv[nt], __fmul_rn(2.f, acc[r]));
                if (pd <= gmr[mt][r]) {
                    int m = mt * 16 + quad * 4 + r;
                    int slot = atomicAdd(&cnt[m], 1);
                    if (slot < CAP) cand[m][slot] = nb + nt * 16 + col;
                }
            }
        }
    }
    __syncthreads();

    // ---- exact rescore (validated fp32 chain), first-index via 64-bit key --
    if (t < 64) {
        float r[8];
#pragma unroll
        for (int q = 0; q < 8; q++) {
            float v = zbase[(size_t)q * NK + t];
            r[q] = __fmul_rn(v, v);
        }
#pragma unroll
        for (int i = 8; i < 64; i += 8)
#pragma unroll
            for (int q = 0; q < 8; q++) {
                float v = zbase[(size_t)(i + q) * NK + t];
                r[q] = __fadd_rn(r[q], __fmul_rn(v, v));
            }
        float s01 = __fadd_rn(r[0], r[1]), s23 = __fadd_rn(r[2], r[3]);
        float s45 = __fadd_rn(r[4], r[5]), s67 = __fadd_rn(r[6], r[7]);
        float t1 = __fadd_rn(__fadd_rn(s01, s23), __fadd_rn(s45, s67));

        int cc = cnt[t];
        unsigned long long kmin = 0xFFFFFFFFFFFFFFFFULL;
        if (cc <= CAP) {
            for (int s = 0; s < cc; s++) {
                int j = cand[t][s];
                const float* cr = cb + (size_t)j * NC;
                float a = 0.f;
#pragma unroll
                for (int c = 0; c < NC; c++)
                    a = __fmaf_rn(zbase[(size_t)c * NK + t], cr[c], a);
                float d = __fsub_rn(__fadd_rn(t1, n32[j]), __fmul_rn(2.f, a));
                unsigned long long key =
                    ((unsigned long long)__float_as_uint(d) << 32) | (unsigned int)j;
                if (key < kmin) kmin = key;
            }
        } else {  // overflow fallback: exact full scan (prob ~0)
            for (int j = 0; j < NCODES; j++) {
                const float* cr = cb + (size_t)j * NC;
                float a = 0.f;
#pragma unroll
                for (int c = 0; c < NC; c++)
                    a = __fmaf_rn(zbase[(size_t)c * NK + t], cr[c], a);
                float d = __fsub_rn(__fadd_rn(t1, n32[j]), __fmul_rn(2.f, a));
                unsigned long long key =
                    ((unsigned long long)__float_as_uint(d) << 32) | (unsigned int)j;
                if (key < kmin) kmin = key;
            }
        }
        int code = (int)(kmin & 0xFFFFFFFFu);
        codearr[t] = code;
        codes_f[vec0 + t] = (float)code;
        atomicAdd(&hist[code], 1);
    }
    __syncthreads();

    // ---- parallel quant epilogue: wave w covers c = w*16..w*16+15 ----------
    double s = 0.0;
    float* ob = outq + (size_t)b * NC * NK + k0;
    const int code = codearr[L];
#pragma unroll
    for (int cc2 = 0; cc2 < 16; cc2++) {
        int c = w * 16 + cc2;
        float zev = zbase[(size_t)c * NK + L];
        float qv = cb[(size_t)code * NC + c];
        ob[(size_t)c * NK + L] = __fadd_rn(zev, __fsub_rn(qv, zev));
        double d = (double)qv - (double)zev;
        s += d * d;
    }
    for (int off = 32; off; off >>= 1) s += __shfl_down(s, off);
    if (L == 0) lsd[w] = s;
    __syncthreads();
    if (t == 0) part[blockIdx.x] = lsd[0] + lsd[1] + lsd[2] + lsd[3];
}

// --- final scalars: loss_vq and perplexity ----------------------------------
__launch_bounds__(1024)
__global__ void k_final(const double* __restrict__ part, const int* __restrict__ hist,
                        float* __restrict__ out) {
    int t = threadIdx.x;                         // 1024 threads = NBLK partials
    double vL = part[t];
    double p = (double)hist[t] * (1.0 / (double)NVEC);
    double vE = p * log(p + 1e-10);
    for (int off = 32; off; off >>= 1) {
        vL += __shfl_down(vL, off);
        vE += __shfl_down(vE, off);
    }
    __shared__ double lsL[16], lsE[16];
    int lane = t & 63, wv = t >> 6;
    if (lane == 0) { lsL[wv] = vL; lsE[wv] = vE; }
    __syncthreads();
    if (t == 0) {
        double SL = 0.0, SE = 0.0;
        for (int i = 0; i < 16; i++) { SL += lsL[i]; SE += lsE[i]; }
        double loss_cb = SL / (double)NELEM;     // == loss_commit numerically
        out[NELEM + NVEC]     = (float)(loss_cb + 0.25 * loss_cb);
        out[NELEM + NVEC + 1] = (float)exp(-SE);
    }
}

extern "C" void kernel_launch(void* const* d_in, const int* in_sizes, int n_in,
                              void* d_out, int out_size, void* d_ws, size_t ws_size,
                              hipStream_t stream) {
    const float* ze = (const float*)d_in[0];
    const float* cb = (const float*)d_in[1];
    float* out = (float*)d_out;
    char* ws = (char*)d_ws;

    int*    hist = (int*)(ws + WS_HIST);
    float*  n32  = (float*)(ws + WS_CBN32);
    double* part = (double*)(ws + WS_PART);
    __bf16* cbbf = (__bf16*)(ws + WS_CBBF);

    float* zq      = out;                 // (32, 64, 2048)
    float* codes_f = out + NELEM;         // (32, 2048) as float

    hipMemsetAsync(hist, 0, NCODES * sizeof(int), stream);
    k_cbprep<<<16, 64, 0, stream>>>(cb, n32, cbbf);
    k_vq<<<NBLK, 256, 0, stream>>>(ze, cb, n32, cbbf, hist, codes_f, zq, part);
    k_final<<<1, 1024, 0, stream>>>(part, hist, out);
}

// Round 6
// 179.369 us; speedup vs baseline: 1.4526x; 1.4526x over previous
//
#include <hip/hip_runtime.h>
#include <math.h>

// Problem constants
#define NB 32
#define NC 64          // CODE_DIM
#define NK 2048
#define NCODES 1024
#define NVEC (NB*NK)          // 65536 vectors
#define NELEM (NB*NC*NK)      // 4194304 elements
#define NBLK (NVEC/64)        // 1024 blocks

#define MARGIN 1.5e-3f        // rigorous bf16-proxy bound 8.7e-4 (validated R5)
#define CAP 32

// ws layout (bytes)
#define WS_HIST  0            // int[1024]      = 4096
#define WS_CBN32 4096         // float[1024]    = 4096
#define WS_PART  8192         // double[1024]   = 8192
#define WS_CBBF  32768        // __bf16[65536]  = 131072

typedef __bf16 bf16x8 __attribute__((ext_vector_type(8)));
typedef float  f32x4  __attribute__((ext_vector_type(4)));
#define MFMA16(A, B, ACC) __builtin_amdgcn_mfma_f32_16x16x32_bf16(A, B, ACC, 0, 0, 0)

// --- codebook prep: numpy-exact fp32 norms (validated R2-R5) + bf16 copy ----
__global__ void k_cbprep(const float* __restrict__ cb, float* __restrict__ n32,
                         __bf16* __restrict__ cbbf) {
    int j = blockIdx.x * 64 + threadIdx.x;   // 16 x 64 = 1024
    const float* cr = cb + (size_t)j * NC;
    float r[8];
#pragma unroll
    for (int q = 0; q < 8; q++) r[q] = __fmul_rn(cr[q], cr[q]);
#pragma unroll
    for (int i = 8; i < 64; i += 8)
#pragma unroll
        for (int q = 0; q < 8; q++)
            r[q] = __fadd_rn(r[q], __fmul_rn(cr[i + q], cr[i + q]));
    float s01 = __fadd_rn(r[0], r[1]), s23 = __fadd_rn(r[2], r[3]);
    float s45 = __fadd_rn(r[4], r[5]), s67 = __fadd_rn(r[6], r[7]);
    n32[j] = __fadd_rn(__fadd_rn(s01, s23), __fadd_rn(s45, s67));
    __bf16* br = cbbf + (size_t)j * NC;
#pragma unroll
    for (int c = 0; c < NC; c++) br[c] = (__bf16)cr[c];
}

// --- fused VQ: single-pass MFMA prefilter -> exact rescore -> quant ---------
// Block: 256 thr = 4 waves; 64 vectors. Wave w owns vectors [w*16, w*16+16)
// and scans ALL 1024 codes (64 tiles of 16). Low register pressure by design:
// af[2]+b0/b1+acc+rmin[4] only. MFMA 16x16x32 bf16 layout (validated R5):
// A[m=lane&15][k=quad*8+j]; B[n=lane&15][k=quad*8+j]; D col=lane&15,
// row=quad*4+reg.
__launch_bounds__(256, 6)
__global__ void k_vq(const float* __restrict__ ze, const float* __restrict__ cb,
                     const float* __restrict__ n32, const __bf16* __restrict__ cbbf,
                     int* __restrict__ hist, float* __restrict__ codes_f,
                     float* __restrict__ outq, double* __restrict__ part) {
    __shared__ int cnt[64];
    __shared__ int cand[64][CAP];
    __shared__ unsigned long long keys2[64][4];
    __shared__ int codearr[64];
    __shared__ double lsd[4];

    const int t = threadIdx.x;
    const int L = t & 63;
    const int w = t >> 6;
    const int quad = L >> 4;
    const int col = L & 15;
    const int vec0 = blockIdx.x * 64;
    const int b = vec0 >> 11;
    const int k0 = vec0 & (NK - 1);
    const float* zbase = ze + (size_t)b * NC * NK + k0;

    if (t < 64) cnt[t] = 0;

    // A-frags for this wave's 16 vectors (vector = w*16+col), bf16 RNE
    bf16x8 af[2];
#pragma unroll
    for (int kt = 0; kt < 2; kt++)
#pragma unroll
        for (int j = 0; j < 8; j++) {
            int c = kt * 32 + quad * 8 + j;
            af[kt][j] = (__bf16)zbase[(size_t)c * NK + w * 16 + col];
        }

    // seed rmin with tile 0's exact proxy min (keeps candidate lists short)
    float rmin[4];
    {
        const __bf16* brow = cbbf + (size_t)col * NC + quad * 8;
        bf16x8 b0 = *(const bf16x8*)(brow);
        bf16x8 b1 = *(const bf16x8*)(brow + 32);
        f32x4 acc = {0.f, 0.f, 0.f, 0.f};
        acc = MFMA16(af[0], b0, acc);
        acc = MFMA16(af[1], b1, acc);
        float nvv = n32[col];
#pragma unroll
        for (int r = 0; r < 4; r++) {
            float pd = __fsub_rn(nvv, __fmul_rn(2.f, acc[r]));
            pd = fminf(pd, __shfl_xor(pd, 1, 16));
            pd = fminf(pd, __shfl_xor(pd, 2, 16));
            pd = fminf(pd, __shfl_xor(pd, 4, 16));
            pd = fminf(pd, __shfl_xor(pd, 8, 16));
            rmin[r] = pd;
        }
    }
    __syncthreads();   // cnt zeroed, all waves ready

    // single pass over 64 code-tiles: capture pd <= rmin(pre) + MARGIN.
    // running min >= final min, so this is a superset of the sufficient set.
    for (int nt = 0; nt < 64; nt++) {
        const __bf16* brow = cbbf + (size_t)(nt * 16 + col) * NC + quad * 8;
        bf16x8 b0 = *(const bf16x8*)(brow);
        bf16x8 b1 = *(const bf16x8*)(brow + 32);
        f32x4 acc = {0.f, 0.f, 0.f, 0.f};
        acc = MFMA16(af[0], b0, acc);
        acc = MFMA16(af[1], b1, acc);
        float nvv = n32[nt * 16 + col];
#pragma unroll
        for (int r = 0; r < 4; r++) {
            float pd = __fsub_rn(nvv, __fmul_rn(2.f, acc[r]));
            if (pd <= rmin[r] + MARGIN) {
                int m = w * 16 + quad * 4 + r;
                int slot = atomicAdd(&cnt[m], 1);
                if (slot < CAP) cand[m][slot] = nt * 16 + col;
            }
            float tm = pd;
            tm = fminf(tm, __shfl_xor(tm, 1, 16));
            tm = fminf(tm, __shfl_xor(tm, 2, 16));
            tm = fminf(tm, __shfl_xor(tm, 4, 16));
            tm = fminf(tm, __shfl_xor(tm, 8, 16));
            rmin[r] = fminf(rmin[r], tm);
        }
    }
    __syncthreads();

    // ---- exact rescore: 4 threads/vector, validated bit-exact fp32 chain ---
    {
        const int v = L;           // vector; this thread handles part w
        // t1 = np.sum(z*z), numpy-exact (redundant x4, bit-identical)
        float r[8];
#pragma unroll
        for (int q = 0; q < 8; q++) {
            float x = zbase[(size_t)q * NK + v];
            r[q] = __fmul_rn(x, x);
        }
#pragma unroll
        for (int i = 8; i < 64; i += 8)
#pragma unroll
            for (int q = 0; q < 8; q++) {
                float x = zbase[(size_t)(i + q) * NK + v];
                r[q] = __fadd_rn(r[q], __fmul_rn(x, x));
            }
        float s01 = __fadd_rn(r[0], r[1]), s23 = __fadd_rn(r[2], r[3]);
        float s45 = __fadd_rn(r[4], r[5]), s67 = __fadd_rn(r[6], r[7]);
        float t1 = __fadd_rn(__fadd_rn(s01, s23), __fadd_rn(s45, s67));

        int cc = cnt[v];
        unsigned long long kmin = 0xFFFFFFFFFFFFFFFFULL;
        if (cc <= CAP) {
            for (int s = w; s < cc; s += 4) {
                int j = cand[v][s];
                const float* cr = cb + (size_t)j * NC;
                float a = 0.f;
#pragma unroll
                for (int c = 0; c < NC; c++)
                    a = __fmaf_rn(zbase[(size_t)c * NK + v], cr[c], a);
                float d = __fsub_rn(__fadd_rn(t1, n32[j]), __fmul_rn(2.f, a));
                unsigned long long key =
                    ((unsigned long long)__float_as_uint(d) << 32) | (unsigned int)j;
                if (key < kmin) kmin = key;
            }
        } else {   // overflow fallback: exact full scan split over 4 threads
            for (int j = w * 256; j < (w + 1) * 256; j++) {
                const float* cr = cb + (size_t)j * NC;
                float a = 0.f;
#pragma unroll
                for (int c = 0; c < NC; c++)
                    a = __fmaf_rn(zbase[(size_t)c * NK + v], cr[c], a);
                float d = __fsub_rn(__fadd_rn(t1, n32[j]), __fmul_rn(2.f, a));
                unsigned long long key =
                    ((unsigned long long)__float_as_uint(d) << 32) | (unsigned int)j;
                if (key < kmin) kmin = key;
            }
        }
        keys2[v][w] = kmin;
    }
    __syncthreads();

    if (t < 64) {   // merge 4 partial keys: min dist, ties -> min idx (np rule)
        unsigned long long kmin = keys2[t][0];
#pragma unroll
        for (int ww = 1; ww < 4; ww++) {
            unsigned long long kk = keys2[t][ww];
            if (kk < kmin) kmin = kk;
        }
        int code = (int)(kmin & 0xFFFFFFFFu);
        codearr[t] = code;
        codes_f[vec0 + t] = (float)code;
        atomicAdd(&hist[code], 1);
    }
    __syncthreads();

    // ---- parallel quant epilogue: wave w covers c = w*16..w*16+15 ----------
    double s = 0.0;
    float* ob = outq + (size_t)b * NC * NK + k0;
    const int code = codearr[L];
#pragma unroll
    for (int cc2 = 0; cc2 < 16; cc2++) {
        int c = w * 16 + cc2;
        float zev = zbase[(size_t)c * NK + L];
        float qv = cb[(size_t)code * NC + c];
        ob[(size_t)c * NK + L] = __fadd_rn(zev, __fsub_rn(qv, zev));
        double d = (double)qv - (double)zev;
        s += d * d;
    }
    for (int off = 32; off; off >>= 1) s += __shfl_down(s, off);
    if (L == 0) lsd[w] = s;
    __syncthreads();
    if (t == 0) part[blockIdx.x] = lsd[0] + lsd[1] + lsd[2] + lsd[3];
}

// --- final scalars: loss_vq and perplexity ----------------------------------
__launch_bounds__(1024)
__global__ void k_final(const double* __restrict__ part, const int* __restrict__ hist,
                        float* __restrict__ out) {
    int t = threadIdx.x;                         // 1024 threads = NBLK partials
    double vL = part[t];
    double p = (double)hist[t] * (1.0 / (double)NVEC);
    double vE = p * log(p + 1e-10);
    for (int off = 32; off; off >>= 1) {
        vL += __shfl_down(vL, off);
        vE += __shfl_down(vE, off);
    }
    __shared__ double lsL[16], lsE[16];
    int lane = t & 63, wv = t >> 6;
    if (lane == 0) { lsL[wv] = vL; lsE[wv] = vE; }
    __syncthreads();
    if (t == 0) {
        double SL = 0.0, SE = 0.0;
        for (int i = 0; i < 16; i++) { SL += lsL[i]; SE += lsE[i]; }
        double loss_cb = SL / (double)NELEM;     // == loss_commit numerically
        out[NELEM + NVEC]     = (float)(loss_cb + 0.25 * loss_cb);
        out[NELEM + NVEC + 1] = (float)exp(-SE);
    }
}

extern "C" void kernel_launch(void* const* d_in, const int* in_sizes, int n_in,
                              void* d_out, int out_size, void* d_ws, size_t ws_size,
                              hipStream_t stream) {
    const float* ze = (const float*)d_in[0];
    const float* cb = (const float*)d_in[1];
    float* out = (float*)d_out;
    char* ws = (char*)d_ws;

    int*    hist = (int*)(ws + WS_HIST);
    float*  n32  = (float*)(ws + WS_CBN32);
    double* part = (double*)(ws + WS_PART);
    __bf16* cbbf = (__bf16*)(ws + WS_CBBF);

    float* zq      = out;                 // (32, 64, 2048)
    float* codes_f = out + NELEM;         // (32, 2048) as float

    hipMemsetAsync(hist, 0, NCODES * sizeof(int), stream);
    k_cbprep<<<16, 64, 0, stream>>>(cb, n32, cbbf);
    k_vq<<<NBLK, 256, 0, stream>>>(ze, cb, n32, cbbf, hist, codes_f, zq, part);
    k_final<<<1, 1024, 0, stream>>>(part, hist, out);
}